// Round 11
// baseline (273.281 us; speedup 1.0000x reference)
//
#include <hip/hip_runtime.h>

#define N_NODES 50000
#define N_EDGES 800000
#define IN_FEATS 256
#define HIDDEN 64
#define OUTF 32
#define SCAN_BLOCKS 196     // ceil(50000/256)

#define NSLICE 64           // edge slices
#define SLICE_E 12500       // N_EDGES / NSLICE
#define NRANGE 4            // node ranges for fill_csr
#define RANGE_N 12800       // nodes per fill range
#define PSTRIDE 51200       // per-slice stride in partial arrays

#define HRANGE 2            // hist ranges (packed 2 nodes/int)
#define HRANGE_N 25600      // nodes per hist range

// ---------------- LDS histogram, 2 nodes packed per int ----------------
__global__ __launch_bounds__(512) void hist_kernel(const int* __restrict__ src,
                                                   const int* __restrict__ dst,
                                                   unsigned char* __restrict__ partial) {
    __shared__ int h[HRANGE_N / 2];     // 12800 ints = 51.2 KB
    const int bid = blockIdx.x;
    const int which = bid & 1;
    const int r = (bid >> 1) & 1;
    const int s = bid >> 2;
    const int tid = threadIdx.x;
    const int lo = r * HRANGE_N;

    for (int i = tid; i < HRANGE_N / 2; i += 512) h[i] = 0;
    __syncthreads();

    const int* arr = which ? dst : src;
    const int e0 = s * SLICE_E;
    for (int j = tid; j < SLICE_E; j += 512) {
        int v = arr[e0 + j] - lo;
        if ((unsigned)v < HRANGE_N) atomicAdd(&h[v >> 1], 1 << ((v & 1) << 4));
    }
    __syncthreads();

    unsigned char* p = partial + (size_t)which * NSLICE * PSTRIDE + (size_t)s * PSTRIDE + lo;
    for (int i = tid; i < HRANGE_N / 2; i += 512) {
        int c = h[i];
        p[i * 2 + 0] = (unsigned char)(c & 0xFFFF);
        p[i * 2 + 1] = (unsigned char)((unsigned)c >> 16);
    }
}

// ---------------- reduce partials -> norms + block-level exclusive scan ----------------
__global__ __launch_bounds__(256) void reduce_scan_kernel(unsigned char* __restrict__ partial,
                                                          int* __restrict__ row_start,
                                                          int* __restrict__ block_sums,
                                                          float* __restrict__ norm_out,
                                                          float* __restrict__ norm_in) {
    __shared__ int sh[256];
    int i = blockIdx.x * 256 + threadIdx.x;
    int run = 0;
    if (i < N_NODES) {
        const unsigned char* ps = partial + i;                      // src partials
        unsigned char* pd = partial + (size_t)NSLICE * PSTRIDE + i; // dst partials
        int so = 0;
#pragma unroll 8
        for (int s = 0; s < NSLICE; ++s) so += ps[(size_t)s * PSTRIDE];
        norm_out[i] = rsqrtf(fmaxf((float)so, 1.0f));
#pragma unroll 8
        for (int s = 0; s < NSLICE; ++s) {
            int c = pd[(size_t)s * PSTRIDE];
            pd[(size_t)s * PSTRIDE] = (unsigned char)run;   // exclusive prefix
            run += c;
        }
        norm_in[i] = rsqrtf(fmaxf((float)run, 1.0f));
    }
    sh[threadIdx.x] = run;
    __syncthreads();
#pragma unroll
    for (int off = 1; off < 256; off <<= 1) {
        int t = (threadIdx.x >= off) ? sh[threadIdx.x - off] : 0;
        __syncthreads();
        sh[threadIdx.x] += t;
        __syncthreads();
    }
    if (i < N_NODES) row_start[i] = sh[threadIdx.x] - run;
    if (threadIdx.x == 255) block_sums[blockIdx.x] = sh[255];
}

// ---------------- scan of block sums folded into the add pass ----------------
__global__ __launch_bounds__(256) void scan3_kernel(int* __restrict__ row_start,
                                                    const int* __restrict__ block_sums) {
    __shared__ int s[256];
    int v = (threadIdx.x < SCAN_BLOCKS) ? block_sums[threadIdx.x] : 0;
    s[threadIdx.x] = v;
    __syncthreads();
#pragma unroll
    for (int off = 1; off < 256; off <<= 1) {
        int t = (threadIdx.x >= off) ? s[threadIdx.x - off] : 0;
        __syncthreads();
        s[threadIdx.x] += t;
        __syncthreads();
    }
    int base = (blockIdx.x == 0) ? 0 : s[blockIdx.x - 1];   // exclusive prefix for this block
    int i = blockIdx.x * 256 + threadIdx.x;
    if (i < N_NODES) row_start[i] += base;
    if (i == 0) row_start[N_NODES] = N_EDGES;
}

// ---------------- CSR fill with LDS cursors: block = (slice, range) ----------------
__global__ __launch_bounds__(512) void fill_csr_kernel(const int* __restrict__ src,
                                                       const int* __restrict__ dst,
                                                       const int* __restrict__ row_start,
                                                       const unsigned char* __restrict__ rel,
                                                       int* __restrict__ csr_src) {
    __shared__ int cur[RANGE_N];        // 51200 B
    const int bid = blockIdx.x;
    const int r = bid & 3;
    const int s = bid >> 2;
    const int tid = threadIdx.x;
    const int lo = r * RANGE_N;

    const unsigned char* relp = rel + (size_t)s * PSTRIDE;
    for (int i = tid; i < RANGE_N; i += 512) {
        int node = lo + i;
        cur[i] = (node < N_NODES) ? row_start[node] + (int)relp[node] : 0;
    }
    __syncthreads();

    const int e0 = s * SLICE_E;
    for (int j = tid; j < SLICE_E; j += 512) {
        int d = dst[e0 + j] - lo;
        if ((unsigned)d < RANGE_N) {
            int pos = atomicAdd(&cur[d], 1);
            csr_src[pos] = src[e0 + j];
        }
    }
}

// ---------------- GEMM1: 64x64 tile, BK=32, 4x4 micro-tile, double-buffered LDS ----------------
// Per chunk: issue global loads for c+1 -> compute chunk c -> store to other buffer -> ONE barrier.
// Prefetch regs live across compute but never across a barrier.
__global__ __launch_bounds__(256, 3) void gemm1_kernel(const float* __restrict__ x,
                                                       const float* __restrict__ W1,
                                                       const float* __restrict__ norm_out,
                                                       float* __restrict__ xw1) {
    __shared__ float As[2][32][68];   // [buf][k][row+pad], 17.4 KiB
    __shared__ float Bs[2][32][68];   // [buf][k][col+pad], 17.4 KiB
    const int tid = threadIdx.x;
    const int n0 = blockIdx.x * 64;
    const int arow = tid & 63;           // A-load row
    const int akc  = tid >> 6;           // 0..3 -> k-offsets akc*8 .. +8
    const int bkk  = tid >> 4;           // 0..15 B-load k base
    const int btc  = tid & 15;           // B-load col4
    const int tr   = tid >> 4;           // rows tr*4..
    const int tc   = tid & 15;           // cols tc*4..

    float acc[4][4];
#pragma unroll
    for (int i = 0; i < 4; ++i)
#pragma unroll
        for (int j = 0; j < 4; ++j) acc[i][j] = 0.f;

    const bool arow_ok = (n0 + arow) < N_NODES;
    const float* xrow = x + (size_t)(n0 + arow) * IN_FEATS;

    float4 va0, va1, vb0, vb1;

#define LOAD_CHUNK(c)                                                            \
    {                                                                            \
        int k0 = (c) * 32;                                                       \
        va0 = make_float4(0.f, 0.f, 0.f, 0.f); va1 = va0;                        \
        if (arow_ok) {                                                           \
            va0 = *(const float4*)(xrow + k0 + akc * 8);                         \
            va1 = *(const float4*)(xrow + k0 + akc * 8 + 4);                     \
        }                                                                        \
        vb0 = *(const float4*)(W1 + (size_t)(k0 + bkk) * HIDDEN + btc * 4);      \
        vb1 = *(const float4*)(W1 + (size_t)(k0 + bkk + 16) * HIDDEN + btc * 4); \
    }

#define STORE_CHUNK(buf)                                                         \
    {                                                                            \
        int kb = akc * 8;                                                        \
        As[buf][kb + 0][arow] = va0.x; As[buf][kb + 1][arow] = va0.y;            \
        As[buf][kb + 2][arow] = va0.z; As[buf][kb + 3][arow] = va0.w;            \
        As[buf][kb + 4][arow] = va1.x; As[buf][kb + 5][arow] = va1.y;            \
        As[buf][kb + 6][arow] = va1.z; As[buf][kb + 7][arow] = va1.w;            \
        *(float4*)&Bs[buf][bkk][btc * 4] = vb0;                                  \
        *(float4*)&Bs[buf][bkk + 16][btc * 4] = vb1;                             \
    }

    // prologue
    LOAD_CHUNK(0);
    STORE_CHUNK(0);
    __syncthreads();

    for (int c = 0; c < 8; ++c) {
        const int cur = c & 1;
        if (c < 7) LOAD_CHUNK(c + 1);       // in flight during compute
#pragma unroll
        for (int kk = 0; kk < 32; ++kk) {
            float4 a4 = *(const float4*)&As[cur][kk][tr * 4];
            float4 b4 = *(const float4*)&Bs[cur][kk][tc * 4];
            acc[0][0] += a4.x * b4.x; acc[0][1] += a4.x * b4.y;
            acc[0][2] += a4.x * b4.z; acc[0][3] += a4.x * b4.w;
            acc[1][0] += a4.y * b4.x; acc[1][1] += a4.y * b4.y;
            acc[1][2] += a4.y * b4.z; acc[1][3] += a4.y * b4.w;
            acc[2][0] += a4.z * b4.x; acc[2][1] += a4.z * b4.y;
            acc[2][2] += a4.z * b4.z; acc[2][3] += a4.z * b4.w;
            acc[3][0] += a4.w * b4.x; acc[3][1] += a4.w * b4.y;
            acc[3][2] += a4.w * b4.z; acc[3][3] += a4.w * b4.w;
        }
        if (c < 7) {
            STORE_CHUNK(cur ^ 1);           // other buffer: safe, laggards are in compute(cur)
            __syncthreads();
        }
    }
#undef LOAD_CHUNK
#undef STORE_CHUNK

#pragma unroll
    for (int i = 0; i < 4; ++i) {
        int row = n0 + tr * 4 + i;
        if (row < N_NODES) {
            float nrm = norm_out[row];
            float4 o = make_float4(acc[i][0] * nrm, acc[i][1] * nrm,
                                   acc[i][2] * nrm, acc[i][3] * nrm);
            *(float4*)(xw1 + (size_t)row * HIDDEN + tc * 4) = o;
        }
    }
}

// ---------------- GEMM2: xw2[n] = (g1[n] @ W2) * norm_out[n] ----------------
__global__ __launch_bounds__(256) void gemm2_kernel(const float* __restrict__ g1,
                                                    const float* __restrict__ W2,
                                                    const float* __restrict__ norm_out,
                                                    float* __restrict__ xw2) {
    __shared__ float gs[8][HIDDEN];
    __shared__ float ws[HIDDEN * OUTF];
    const int tid = threadIdx.x;
    const int n0 = blockIdx.x * 8;

#pragma unroll
    for (int i = 0; i < 8; ++i) ws[tid + i * 256] = W2[tid + i * 256];
    const float4* gv = (const float4*)(g1 + (size_t)n0 * HIDDEN);
    if (tid < 128) ((float4*)&gs[0][0])[tid] = gv[tid];
    __syncthreads();

    const int o = tid & 31;
    const int r = tid >> 5;
    float acc = 0.f;
#pragma unroll
    for (int k = 0; k < HIDDEN; ++k) acc += gs[r][k] * ws[k * OUTF + o];
    xw2[(size_t)(n0 + r) * OUTF + o] = acc * norm_out[n0 + r];
}

// ---------------- gather 64 feats: one wave per node, 8-deep MLP ----------------
__global__ __launch_bounds__(256) void gather64_kernel(const int* __restrict__ row_start,
                                                       const int* __restrict__ csr_src,
                                                       const float* __restrict__ xw,
                                                       const float* __restrict__ norm_in,
                                                       const float* __restrict__ b,
                                                       float* __restrict__ g) {
    int n = blockIdx.x * 4 + (threadIdx.x >> 6);
    if (n >= N_NODES) return;
    int lane = threadIdx.x & 63;
    int beg = row_start[n], end = row_start[n + 1];
    float acc = 0.f;
    int i = beg;
    for (; i + 8 <= end; i += 8) {
        int s0 = csr_src[i + 0], s1 = csr_src[i + 1];
        int s2 = csr_src[i + 2], s3 = csr_src[i + 3];
        int s4 = csr_src[i + 4], s5 = csr_src[i + 5];
        int s6 = csr_src[i + 6], s7 = csr_src[i + 7];
        float v0 = xw[(size_t)s0 * 64 + lane];
        float v1 = xw[(size_t)s1 * 64 + lane];
        float v2 = xw[(size_t)s2 * 64 + lane];
        float v3 = xw[(size_t)s3 * 64 + lane];
        float v4 = xw[(size_t)s4 * 64 + lane];
        float v5 = xw[(size_t)s5 * 64 + lane];
        float v6 = xw[(size_t)s6 * 64 + lane];
        float v7 = xw[(size_t)s7 * 64 + lane];
        acc += ((v0 + v1) + (v2 + v3)) + ((v4 + v5) + (v6 + v7));
    }
    for (; i < end; ++i) acc += xw[(size_t)csr_src[i] * 64 + lane];
    g[(size_t)n * 64 + lane] = fmaxf(acc * norm_in[n] + b[lane], 0.f);
}

// ---------------- gather 32 feats: half-wave per node, 8-deep MLP ----------------
__global__ __launch_bounds__(256) void gather32_kernel(const int* __restrict__ row_start,
                                                       const int* __restrict__ csr_src,
                                                       const float* __restrict__ xw,
                                                       const float* __restrict__ norm_in,
                                                       const float* __restrict__ b,
                                                       float* __restrict__ g) {
    int n = blockIdx.x * 8 + (threadIdx.x >> 5);
    if (n >= N_NODES) return;
    int lane = threadIdx.x & 31;
    int beg = row_start[n], end = row_start[n + 1];
    float acc = 0.f;
    int i = beg;
    for (; i + 8 <= end; i += 8) {
        int s0 = csr_src[i + 0], s1 = csr_src[i + 1];
        int s2 = csr_src[i + 2], s3 = csr_src[i + 3];
        int s4 = csr_src[i + 4], s5 = csr_src[i + 5];
        int s6 = csr_src[i + 6], s7 = csr_src[i + 7];
        float v0 = xw[(size_t)s0 * 32 + lane];
        float v1 = xw[(size_t)s1 * 32 + lane];
        float v2 = xw[(size_t)s2 * 32 + lane];
        float v3 = xw[(size_t)s3 * 32 + lane];
        float v4 = xw[(size_t)s4 * 32 + lane];
        float v5 = xw[(size_t)s5 * 32 + lane];
        float v6 = xw[(size_t)s6 * 32 + lane];
        float v7 = xw[(size_t)s7 * 32 + lane];
        acc += ((v0 + v1) + (v2 + v3)) + ((v4 + v5) + (v6 + v7));
    }
    for (; i < end; ++i) acc += xw[(size_t)csr_src[i] * 32 + lane];
    g[(size_t)n * 32 + lane] = fmaxf(acc * norm_in[n] + b[lane], 0.f);
}

// ---------------- final projection ----------------
__global__ __launch_bounds__(32) void init_out_kernel(float* __restrict__ out,
                                                      const float* __restrict__ fc_b) {
    out[threadIdx.x] = fc_b[0];
}

__global__ __launch_bounds__(256) void reduce_kernel(const float* __restrict__ g2,
                                                     const float* __restrict__ fc_w,
                                                     float* __restrict__ out) {
    __shared__ float s[OUTF];
    const int tid = threadIdx.x;
    if (tid < OUTF) s[tid] = 0.f;
    __syncthreads();

    const int f4 = tid & 7;
    int n = blockIdx.x * 32 + (tid >> 3);
    const int stride = gridDim.x * 32;
    float ax = 0.f, ay = 0.f, az = 0.f, aw = 0.f;
    for (; n < N_NODES; n += stride) {
        float w = fc_w[n];
        float4 g = ((const float4*)(g2 + (size_t)n * OUTF))[f4];
        ax += g.x * w; ay += g.y * w; az += g.z * w; aw += g.w * w;
    }
    atomicAdd(&s[f4 * 4 + 0], ax);
    atomicAdd(&s[f4 * 4 + 1], ay);
    atomicAdd(&s[f4 * 4 + 2], az);
    atomicAdd(&s[f4 * 4 + 3], aw);
    __syncthreads();
    if (tid < OUTF) atomicAdd(&out[tid], s[tid]);
}

extern "C" void kernel_launch(void* const* d_in, const int* in_sizes, int n_in,
                              void* d_out, int out_size, void* d_ws, size_t ws_size,
                              hipStream_t stream) {
    const float* x    = (const float*)d_in[0];
    const int*   src  = (const int*)d_in[1];
    const int*   dst  = (const int*)d_in[2];
    const float* W1   = (const float*)d_in[3];
    const float* b1   = (const float*)d_in[4];
    const float* W2   = (const float*)d_in[5];
    const float* b2   = (const float*)d_in[6];
    const float* fc_w = (const float*)d_in[7];
    const float* fc_b = (const float*)d_in[8];
    float* out = (float*)d_out;

    // ---- workspace layout: ints | floats | u8 partials ----
    int* ip = (int*)d_ws;
    int* csr_src      = ip;                 // 800000
    int* row_start    = ip + 800000;        // 50001
    int* block_sums   = ip + 850001;        // 256 (+3 pad)
    float* fp = (float*)(ip + 850260);
    float* xw_buf   = fp;                   // 3.2M floats
    float* g_buf    = fp + 3200000;         // 3.2M floats
    float* norm_out = fp + 6400000;         // 50000
    float* norm_in  = fp + 6450000;         // 50000
    unsigned char* partial = (unsigned char*)(fp + 6500000); // 2*64*51200 B
    unsigned char* rel = partial + (size_t)NSLICE * PSTRIDE; // dst partials -> rel prefixes

    // ---- CSR build (no global atomics anywhere) ----
    hist_kernel<<<NSLICE * HRANGE * 2, 512, 0, stream>>>(src, dst, partial);
    reduce_scan_kernel<<<SCAN_BLOCKS, 256, 0, stream>>>(partial, row_start, block_sums,
                                                        norm_out, norm_in);
    scan3_kernel<<<SCAN_BLOCKS, 256, 0, stream>>>(row_start, block_sums);
    fill_csr_kernel<<<NSLICE * NRANGE, 512, 0, stream>>>(src, dst, row_start, rel, csr_src);

    // ---- layer 1 ----
    gemm1_kernel<<<(N_NODES + 63) / 64, 256, 0, stream>>>(x, W1, norm_out, xw_buf);
    gather64_kernel<<<(N_NODES + 3) / 4, 256, 0, stream>>>(row_start, csr_src, xw_buf,
                                                           norm_in, b1, g_buf);

    // ---- layer 2 ----
    gemm2_kernel<<<N_NODES / 8, 256, 0, stream>>>(g_buf, W2, norm_out, xw_buf);
    gather32_kernel<<<(N_NODES + 7) / 8, 256, 0, stream>>>(row_start, csr_src, xw_buf,
                                                           norm_in, b2, g_buf);

    // ---- final projection ----
    init_out_kernel<<<1, 32, 0, stream>>>(out, fc_b);
    reduce_kernel<<<512, 256, 0, stream>>>(g_buf, fc_w, out);
}

// Round 12
// 171.099 us; speedup vs baseline: 1.5972x; 1.5972x over previous
//
#include <hip/hip_runtime.h>

#define N_NODES 50000
#define N_EDGES 800000
#define IN_FEATS 256
#define HIDDEN 64
#define OUTF 32
#define SCAN_BLOCKS 196     // ceil(50000/256)

#define NSLICE 64           // edge slices
#define SLICE_E 12500       // N_EDGES / NSLICE
#define NRANGE 4            // node ranges for fill_csr
#define RANGE_N 12800       // nodes per fill range
#define PSTRIDE 51200       // per-slice stride in partial arrays

#define HRANGE 2            // hist ranges (packed 2 nodes/int)
#define HRANGE_N 25600      // nodes per hist range

typedef __attribute__((ext_vector_type(8))) short bf16x8;
typedef __attribute__((ext_vector_type(4))) float f32x4;

// pack two floats into two bf16 (RNE) in one u32: lo = a, hi = b
__device__ __forceinline__ unsigned f2bf_pk(float a, float b) {
    union { float f; unsigned u; } x, y;
    x.f = a; y.f = b;
    unsigned lo = x.u + 0x7FFFu + ((x.u >> 16) & 1u);
    unsigned hi = y.u + 0x7FFFu + ((y.u >> 16) & 1u);
    return (lo >> 16) | (hi & 0xFFFF0000u);
}

// ---------------- LDS histogram, 2 nodes packed per int ----------------
__global__ __launch_bounds__(512) void hist_kernel(const int* __restrict__ src,
                                                   const int* __restrict__ dst,
                                                   unsigned char* __restrict__ partial) {
    __shared__ int h[HRANGE_N / 2];     // 12800 ints = 51.2 KB
    const int bid = blockIdx.x;
    const int which = bid & 1;
    const int r = (bid >> 1) & 1;
    const int s = bid >> 2;
    const int tid = threadIdx.x;
    const int lo = r * HRANGE_N;

    for (int i = tid; i < HRANGE_N / 2; i += 512) h[i] = 0;
    __syncthreads();

    const int* arr = which ? dst : src;
    const int e0 = s * SLICE_E;
    for (int j = tid; j < SLICE_E; j += 512) {
        int v = arr[e0 + j] - lo;
        if ((unsigned)v < HRANGE_N) atomicAdd(&h[v >> 1], 1 << ((v & 1) << 4));
    }
    __syncthreads();

    unsigned char* p = partial + (size_t)which * NSLICE * PSTRIDE + (size_t)s * PSTRIDE + lo;
    for (int i = tid; i < HRANGE_N / 2; i += 512) {
        int c = h[i];
        p[i * 2 + 0] = (unsigned char)(c & 0xFFFF);
        p[i * 2 + 1] = (unsigned char)((unsigned)c >> 16);
    }
}

// ---------------- reduce partials -> norms + block-level exclusive scan ----------------
__global__ __launch_bounds__(256) void reduce_scan_kernel(unsigned char* __restrict__ partial,
                                                          int* __restrict__ row_start,
                                                          int* __restrict__ block_sums,
                                                          float* __restrict__ norm_out,
                                                          float* __restrict__ norm_in) {
    __shared__ int sh[256];
    int i = blockIdx.x * 256 + threadIdx.x;
    int run = 0;
    if (i < N_NODES) {
        const unsigned char* ps = partial + i;                      // src partials
        unsigned char* pd = partial + (size_t)NSLICE * PSTRIDE + i; // dst partials
        int so = 0;
#pragma unroll 8
        for (int s = 0; s < NSLICE; ++s) so += ps[(size_t)s * PSTRIDE];
        norm_out[i] = rsqrtf(fmaxf((float)so, 1.0f));
#pragma unroll 8
        for (int s = 0; s < NSLICE; ++s) {
            int c = pd[(size_t)s * PSTRIDE];
            pd[(size_t)s * PSTRIDE] = (unsigned char)run;   // exclusive prefix
            run += c;
        }
        norm_in[i] = rsqrtf(fmaxf((float)run, 1.0f));
    }
    sh[threadIdx.x] = run;
    __syncthreads();
#pragma unroll
    for (int off = 1; off < 256; off <<= 1) {
        int t = (threadIdx.x >= off) ? sh[threadIdx.x - off] : 0;
        __syncthreads();
        sh[threadIdx.x] += t;
        __syncthreads();
    }
    if (i < N_NODES) row_start[i] = sh[threadIdx.x] - run;
    if (threadIdx.x == 255) block_sums[blockIdx.x] = sh[255];
}

// ---------------- scan of block sums folded into the add pass ----------------
__global__ __launch_bounds__(256) void scan3_kernel(int* __restrict__ row_start,
                                                    const int* __restrict__ block_sums) {
    __shared__ int s[256];
    int v = (threadIdx.x < SCAN_BLOCKS) ? block_sums[threadIdx.x] : 0;
    s[threadIdx.x] = v;
    __syncthreads();
#pragma unroll
    for (int off = 1; off < 256; off <<= 1) {
        int t = (threadIdx.x >= off) ? s[threadIdx.x - off] : 0;
        __syncthreads();
        s[threadIdx.x] += t;
        __syncthreads();
    }
    int base = (blockIdx.x == 0) ? 0 : s[blockIdx.x - 1];   // exclusive prefix for this block
    int i = blockIdx.x * 256 + threadIdx.x;
    if (i < N_NODES) row_start[i] += base;
    if (i == 0) row_start[N_NODES] = N_EDGES;
}

// ---------------- CSR fill with LDS cursors: block = (slice, range) ----------------
__global__ __launch_bounds__(512) void fill_csr_kernel(const int* __restrict__ src,
                                                       const int* __restrict__ dst,
                                                       const int* __restrict__ row_start,
                                                       const unsigned char* __restrict__ rel,
                                                       int* __restrict__ csr_src) {
    __shared__ int cur[RANGE_N];        // 51200 B
    const int bid = blockIdx.x;
    const int r = bid & 3;
    const int s = bid >> 2;
    const int tid = threadIdx.x;
    const int lo = r * RANGE_N;

    const unsigned char* relp = rel + (size_t)s * PSTRIDE;
    for (int i = tid; i < RANGE_N; i += 512) {
        int node = lo + i;
        cur[i] = (node < N_NODES) ? row_start[node] + (int)relp[node] : 0;
    }
    __syncthreads();

    const int e0 = s * SLICE_E;
    for (int j = tid; j < SLICE_E; j += 512) {
        int d = dst[e0 + j] - lo;
        if ((unsigned)d < RANGE_N) {
            int pos = atomicAdd(&cur[d], 1);
            csr_src[pos] = src[e0 + j];
        }
    }
}

// ---------------- GEMM1: bf16 MFMA 16x16x32, 64x64 tile, 2 chunks of BK=128 ----------------
// A fragment: row=lane&15, k=(lane>>4)*8+i.  B via transposed-W LDS: col=lane&15.
// D: col=lane&15, row=(lane>>4)*4+reg  [verified layouts, learn_hip m89/m91].
#define AST 136    // shorts per LDS row: 128 k + 8 pad (272 B rows -> 2-way-free b128 reads)
__global__ __launch_bounds__(256) void gemm1_kernel(const float* __restrict__ x,
                                                    const float* __restrict__ W1,
                                                    const float* __restrict__ norm_out,
                                                    float* __restrict__ xw1) {
    __shared__ short As[64 * AST];   // x tile, bf16, [row][k]
    __shared__ short Bt[64 * AST];   // W1 chunk, bf16, [col][k]
    const int tid = threadIdx.x;
    const int n0 = blockIdx.x * 64;

    const f32x4 zero4 = {0.f, 0.f, 0.f, 0.f};
    f32x4 acc[4] = {zero4, zero4, zero4, zero4};

    const int srow = tid >> 2;          // staging row 0..63
    const int sseg = tid & 3;           // 32-k segment
    const int grow = n0 + srow;
    const bool grow_ok = grow < N_NODES;

    const int w = tid >> 6;             // wave 0..3 -> rows w*16..
    const int l = tid & 63;

    for (int c = 0; c < 2; ++c) {
        if (c) __syncthreads();         // protect LDS from previous chunk's readers
        // ---- stage x chunk: 64 rows x 128 k -> bf16 ----
        {
            const float* xp = x + (size_t)grow * IN_FEATS + c * 128 + sseg * 32;
            short* ap = As + srow * AST + sseg * 32;
#pragma unroll
            for (int j = 0; j < 8; ++j) {
                float4 v = make_float4(0.f, 0.f, 0.f, 0.f);
                if (grow_ok) v = *(const float4*)(xp + j * 4);
                unsigned p0 = f2bf_pk(v.x, v.y);
                unsigned p1 = f2bf_pk(v.z, v.w);
                *(uint2*)(ap + j * 4) = make_uint2(p0, p1);
            }
        }
        // ---- stage W1 chunk transposed: Bt[col][k], k-pairs packed ----
        {
#pragma unroll
            for (int it = 0; it < 16; ++it) {
                int flat = tid + it * 256;
                int kp = flat >> 6;             // k-pair 0..63
                int col = flat & 63;
                int k = c * 128 + kp * 2;
                float w0 = W1[(size_t)k * HIDDEN + col];
                float w1 = W1[(size_t)(k + 1) * HIDDEN + col];
                *(unsigned*)(Bt + col * AST + kp * 2) = f2bf_pk(w0, w1);
            }
        }
        __syncthreads();

        // ---- MFMA: 4 k-steps x 4 col-tiles ----
        const short* ap = As + (w * 16 + (l & 15)) * AST + (l >> 4) * 8;
        const short* bp = Bt + (l & 15) * AST + (l >> 4) * 8;
#pragma unroll
        for (int ks = 0; ks < 4; ++ks) {
            bf16x8 af = *(const bf16x8*)(ap + ks * 32);
#pragma unroll
            for (int ct = 0; ct < 4; ++ct) {
                bf16x8 bfv = *(const bf16x8*)(bp + ct * 16 * AST + ks * 32);
                acc[ct] = __builtin_amdgcn_mfma_f32_16x16x32_bf16(af, bfv, acc[ct], 0, 0, 0);
            }
        }
    }

    // ---- epilogue: D[row][col], row=(l>>4)*4+j, col=l&15 ----
    const int rbase = n0 + w * 16 + (l >> 4) * 4;
    const int cbase = l & 15;
#pragma unroll
    for (int j = 0; j < 4; ++j) {
        int row = rbase + j;
        if (row < N_NODES) {
            float nrm = norm_out[row];
            float* orow = xw1 + (size_t)row * HIDDEN + cbase;
#pragma unroll
            for (int ct = 0; ct < 4; ++ct)
                orow[ct * 16] = acc[ct][j] * nrm;
        }
    }
}

// ---------------- GEMM2: xw2[n] = (g1[n] @ W2) * norm_out[n] ----------------
__global__ __launch_bounds__(256) void gemm2_kernel(const float* __restrict__ g1,
                                                    const float* __restrict__ W2,
                                                    const float* __restrict__ norm_out,
                                                    float* __restrict__ xw2) {
    __shared__ float gs[8][HIDDEN];
    __shared__ float ws[HIDDEN * OUTF];
    const int tid = threadIdx.x;
    const int n0 = blockIdx.x * 8;

#pragma unroll
    for (int i = 0; i < 8; ++i) ws[tid + i * 256] = W2[tid + i * 256];
    const float4* gv = (const float4*)(g1 + (size_t)n0 * HIDDEN);
    if (tid < 128) ((float4*)&gs[0][0])[tid] = gv[tid];
    __syncthreads();

    const int o = tid & 31;
    const int r = tid >> 5;
    float acc = 0.f;
#pragma unroll
    for (int k = 0; k < HIDDEN; ++k) acc += gs[r][k] * ws[k * OUTF + o];
    xw2[(size_t)(n0 + r) * OUTF + o] = acc * norm_out[n0 + r];
}

// ---------------- gather 64 feats: one wave per node, 8-deep MLP ----------------
__global__ __launch_bounds__(256) void gather64_kernel(const int* __restrict__ row_start,
                                                       const int* __restrict__ csr_src,
                                                       const float* __restrict__ xw,
                                                       const float* __restrict__ norm_in,
                                                       const float* __restrict__ b,
                                                       float* __restrict__ g) {
    int n = blockIdx.x * 4 + (threadIdx.x >> 6);
    if (n >= N_NODES) return;
    int lane = threadIdx.x & 63;
    int beg = row_start[n], end = row_start[n + 1];
    float acc = 0.f;
    int i = beg;
    for (; i + 8 <= end; i += 8) {
        int s0 = csr_src[i + 0], s1 = csr_src[i + 1];
        int s2 = csr_src[i + 2], s3 = csr_src[i + 3];
        int s4 = csr_src[i + 4], s5 = csr_src[i + 5];
        int s6 = csr_src[i + 6], s7 = csr_src[i + 7];
        float v0 = xw[(size_t)s0 * 64 + lane];
        float v1 = xw[(size_t)s1 * 64 + lane];
        float v2 = xw[(size_t)s2 * 64 + lane];
        float v3 = xw[(size_t)s3 * 64 + lane];
        float v4 = xw[(size_t)s4 * 64 + lane];
        float v5 = xw[(size_t)s5 * 64 + lane];
        float v6 = xw[(size_t)s6 * 64 + lane];
        float v7 = xw[(size_t)s7 * 64 + lane];
        acc += ((v0 + v1) + (v2 + v3)) + ((v4 + v5) + (v6 + v7));
    }
    for (; i < end; ++i) acc += xw[(size_t)csr_src[i] * 64 + lane];
    g[(size_t)n * 64 + lane] = fmaxf(acc * norm_in[n] + b[lane], 0.f);
}

// ---------------- gather 32 feats: half-wave per node, 8-deep MLP ----------------
__global__ __launch_bounds__(256) void gather32_kernel(const int* __restrict__ row_start,
                                                       const int* __restrict__ csr_src,
                                                       const float* __restrict__ xw,
                                                       const float* __restrict__ norm_in,
                                                       const float* __restrict__ b,
                                                       float* __restrict__ g) {
    int n = blockIdx.x * 8 + (threadIdx.x >> 5);
    if (n >= N_NODES) return;
    int lane = threadIdx.x & 31;
    int beg = row_start[n], end = row_start[n + 1];
    float acc = 0.f;
    int i = beg;
    for (; i + 8 <= end; i += 8) {
        int s0 = csr_src[i + 0], s1 = csr_src[i + 1];
        int s2 = csr_src[i + 2], s3 = csr_src[i + 3];
        int s4 = csr_src[i + 4], s5 = csr_src[i + 5];
        int s6 = csr_src[i + 6], s7 = csr_src[i + 7];
        float v0 = xw[(size_t)s0 * 32 + lane];
        float v1 = xw[(size_t)s1 * 32 + lane];
        float v2 = xw[(size_t)s2 * 32 + lane];
        float v3 = xw[(size_t)s3 * 32 + lane];
        float v4 = xw[(size_t)s4 * 32 + lane];
        float v5 = xw[(size_t)s5 * 32 + lane];
        float v6 = xw[(size_t)s6 * 32 + lane];
        float v7 = xw[(size_t)s7 * 32 + lane];
        acc += ((v0 + v1) + (v2 + v3)) + ((v4 + v5) + (v6 + v7));
    }
    for (; i < end; ++i) acc += xw[(size_t)csr_src[i] * 32 + lane];
    g[(size_t)n * 32 + lane] = fmaxf(acc * norm_in[n] + b[lane], 0.f);
}

// ---------------- final projection ----------------
__global__ __launch_bounds__(32) void init_out_kernel(float* __restrict__ out,
                                                      const float* __restrict__ fc_b) {
    out[threadIdx.x] = fc_b[0];
}

__global__ __launch_bounds__(256) void reduce_kernel(const float* __restrict__ g2,
                                                     const float* __restrict__ fc_w,
                                                     float* __restrict__ out) {
    __shared__ float s[OUTF];
    const int tid = threadIdx.x;
    if (tid < OUTF) s[tid] = 0.f;
    __syncthreads();

    const int f4 = tid & 7;
    int n = blockIdx.x * 32 + (tid >> 3);
    const int stride = gridDim.x * 32;
    float ax = 0.f, ay = 0.f, az = 0.f, aw = 0.f;
    for (; n < N_NODES; n += stride) {
        float w = fc_w[n];
        float4 g = ((const float4*)(g2 + (size_t)n * OUTF))[f4];
        ax += g.x * w; ay += g.y * w; az += g.z * w; aw += g.w * w;
    }
    atomicAdd(&s[f4 * 4 + 0], ax);
    atomicAdd(&s[f4 * 4 + 1], ay);
    atomicAdd(&s[f4 * 4 + 2], az);
    atomicAdd(&s[f4 * 4 + 3], aw);
    __syncthreads();
    if (tid < OUTF) atomicAdd(&out[tid], s[tid]);
}

extern "C" void kernel_launch(void* const* d_in, const int* in_sizes, int n_in,
                              void* d_out, int out_size, void* d_ws, size_t ws_size,
                              hipStream_t stream) {
    const float* x    = (const float*)d_in[0];
    const int*   src  = (const int*)d_in[1];
    const int*   dst  = (const int*)d_in[2];
    const float* W1   = (const float*)d_in[3];
    const float* b1   = (const float*)d_in[4];
    const float* W2   = (const float*)d_in[5];
    const float* b2   = (const float*)d_in[6];
    const float* fc_w = (const float*)d_in[7];
    const float* fc_b = (const float*)d_in[8];
    float* out = (float*)d_out;

    // ---- workspace layout: ints | floats | u8 partials ----
    int* ip = (int*)d_ws;
    int* csr_src      = ip;                 // 800000
    int* row_start    = ip + 800000;        // 50001
    int* block_sums   = ip + 850001;        // 256 (+3 pad)
    float* fp = (float*)(ip + 850260);
    float* xw_buf   = fp;                   // 3.2M floats
    float* g_buf    = fp + 3200000;         // 3.2M floats
    float* norm_out = fp + 6400000;         // 50000
    float* norm_in  = fp + 6450000;         // 50000
    unsigned char* partial = (unsigned char*)(fp + 6500000); // 2*64*51200 B
    unsigned char* rel = partial + (size_t)NSLICE * PSTRIDE; // dst partials -> rel prefixes

    // ---- CSR build (no global atomics anywhere) ----
    hist_kernel<<<NSLICE * HRANGE * 2, 512, 0, stream>>>(src, dst, partial);
    reduce_scan_kernel<<<SCAN_BLOCKS, 256, 0, stream>>>(partial, row_start, block_sums,
                                                        norm_out, norm_in);
    scan3_kernel<<<SCAN_BLOCKS, 256, 0, stream>>>(row_start, block_sums);
    fill_csr_kernel<<<NSLICE * NRANGE, 512, 0, stream>>>(src, dst, row_start, rel, csr_src);

    // ---- layer 1 ----
    gemm1_kernel<<<(N_NODES + 63) / 64, 256, 0, stream>>>(x, W1, norm_out, xw_buf);
    gather64_kernel<<<(N_NODES + 3) / 4, 256, 0, stream>>>(row_start, csr_src, xw_buf,
                                                           norm_in, b1, g_buf);

    // ---- layer 2 ----
    gemm2_kernel<<<N_NODES / 8, 256, 0, stream>>>(g_buf, W2, norm_out, xw_buf);
    gather32_kernel<<<(N_NODES + 7) / 8, 256, 0, stream>>>(row_start, csr_src, xw_buf,
                                                           norm_in, b2, g_buf);

    // ---- final projection ----
    init_out_kernel<<<1, 32, 0, stream>>>(out, fc_b);
    reduce_kernel<<<512, 256, 0, stream>>>(g_buf, fc_w, out);
}

// Round 13
// 160.751 us; speedup vs baseline: 1.7000x; 1.0644x over previous
//
#include <hip/hip_runtime.h>

#define N_NODES 50000
#define N_EDGES 800000
#define IN_FEATS 256
#define HIDDEN 64
#define OUTF 32
#define SCAN_BLOCKS 196     // ceil(50000/256)

#define NSLICE 64           // edge slices
#define SLICE_E 12500       // N_EDGES / NSLICE
#define NRANGE 4            // node ranges for fill_csr
#define RANGE_N 12800       // nodes per fill range
#define PSTRIDE 51200       // per-slice stride in partial arrays

#define HRANGE 2            // hist ranges (packed 2 nodes/int)
#define HRANGE_N 25600      // nodes per hist range

typedef __attribute__((ext_vector_type(8))) short bf16x8;
typedef __attribute__((ext_vector_type(4))) float f32x4;
typedef unsigned short u16;

// pack two floats into two bf16 (RNE) in one u32: lo = a, hi = b
__device__ __forceinline__ unsigned f2bf_pk(float a, float b) {
    union { float f; unsigned u; } x, y;
    x.f = a; y.f = b;
    unsigned lo = x.u + 0x7FFFu + ((x.u >> 16) & 1u);
    unsigned hi = y.u + 0x7FFFu + ((y.u >> 16) & 1u);
    return (lo >> 16) | (hi & 0xFFFF0000u);
}
__device__ __forceinline__ u16 f2bf(float a) {
    union { float f; unsigned u; } x;
    x.f = a;
    return (u16)((x.u + 0x7FFFu + ((x.u >> 16) & 1u)) >> 16);
}
__device__ __forceinline__ float bf2f(u16 h) {
    union { unsigned u; float f; } x;
    x.u = ((unsigned)h) << 16;
    return x.f;
}

// ---------------- LDS histogram, 2 nodes packed per int ----------------
__global__ __launch_bounds__(512) void hist_kernel(const int* __restrict__ src,
                                                   const int* __restrict__ dst,
                                                   unsigned char* __restrict__ partial) {
    __shared__ int h[HRANGE_N / 2];     // 12800 ints = 51.2 KB
    const int bid = blockIdx.x;
    const int which = bid & 1;
    const int r = (bid >> 1) & 1;
    const int s = bid >> 2;
    const int tid = threadIdx.x;
    const int lo = r * HRANGE_N;

    for (int i = tid; i < HRANGE_N / 2; i += 512) h[i] = 0;
    __syncthreads();

    const int* arr = which ? dst : src;
    const int e0 = s * SLICE_E;
    for (int j = tid; j < SLICE_E; j += 512) {
        int v = arr[e0 + j] - lo;
        if ((unsigned)v < HRANGE_N) atomicAdd(&h[v >> 1], 1 << ((v & 1) << 4));
    }
    __syncthreads();

    unsigned char* p = partial + (size_t)which * NSLICE * PSTRIDE + (size_t)s * PSTRIDE + lo;
    for (int i = tid; i < HRANGE_N / 2; i += 512) {
        int c = h[i];
        p[i * 2 + 0] = (unsigned char)(c & 0xFFFF);
        p[i * 2 + 1] = (unsigned char)((unsigned)c >> 16);
    }
}

// ---------------- reduce partials -> norms + block-level exclusive scan ----------------
__global__ __launch_bounds__(256) void reduce_scan_kernel(unsigned char* __restrict__ partial,
                                                          int* __restrict__ row_start,
                                                          int* __restrict__ block_sums,
                                                          float* __restrict__ norm_out,
                                                          float* __restrict__ norm_in) {
    __shared__ int sh[256];
    int i = blockIdx.x * 256 + threadIdx.x;
    int run = 0;
    if (i < N_NODES) {
        const unsigned char* ps = partial + i;                      // src partials
        unsigned char* pd = partial + (size_t)NSLICE * PSTRIDE + i; // dst partials
        int so = 0;
#pragma unroll 8
        for (int s = 0; s < NSLICE; ++s) so += ps[(size_t)s * PSTRIDE];
        norm_out[i] = rsqrtf(fmaxf((float)so, 1.0f));
#pragma unroll 8
        for (int s = 0; s < NSLICE; ++s) {
            int c = pd[(size_t)s * PSTRIDE];
            pd[(size_t)s * PSTRIDE] = (unsigned char)run;   // exclusive prefix
            run += c;
        }
        norm_in[i] = rsqrtf(fmaxf((float)run, 1.0f));
    }
    sh[threadIdx.x] = run;
    __syncthreads();
#pragma unroll
    for (int off = 1; off < 256; off <<= 1) {
        int t = (threadIdx.x >= off) ? sh[threadIdx.x - off] : 0;
        __syncthreads();
        sh[threadIdx.x] += t;
        __syncthreads();
    }
    if (i < N_NODES) row_start[i] = sh[threadIdx.x] - run;
    if (threadIdx.x == 255) block_sums[blockIdx.x] = sh[255];
}

// ---------------- scan of block sums folded into the add pass ----------------
__global__ __launch_bounds__(256) void scan3_kernel(int* __restrict__ row_start,
                                                    const int* __restrict__ block_sums) {
    __shared__ int s[256];
    int v = (threadIdx.x < SCAN_BLOCKS) ? block_sums[threadIdx.x] : 0;
    s[threadIdx.x] = v;
    __syncthreads();
#pragma unroll
    for (int off = 1; off < 256; off <<= 1) {
        int t = (threadIdx.x >= off) ? s[threadIdx.x - off] : 0;
        __syncthreads();
        s[threadIdx.x] += t;
        __syncthreads();
    }
    int base = (blockIdx.x == 0) ? 0 : s[blockIdx.x - 1];   // exclusive prefix for this block
    int i = blockIdx.x * 256 + threadIdx.x;
    if (i < N_NODES) row_start[i] += base;
    if (i == 0) row_start[N_NODES] = N_EDGES;
}

// ---------------- CSR fill with LDS cursors: block = (slice, range) ----------------
__global__ __launch_bounds__(512) void fill_csr_kernel(const int* __restrict__ src,
                                                       const int* __restrict__ dst,
                                                       const int* __restrict__ row_start,
                                                       const unsigned char* __restrict__ rel,
                                                       int* __restrict__ csr_src) {
    __shared__ int cur[RANGE_N];        // 51200 B
    const int bid = blockIdx.x;
    const int r = bid & 3;
    const int s = bid >> 2;
    const int tid = threadIdx.x;
    const int lo = r * RANGE_N;

    const unsigned char* relp = rel + (size_t)s * PSTRIDE;
    for (int i = tid; i < RANGE_N; i += 512) {
        int node = lo + i;
        cur[i] = (node < N_NODES) ? row_start[node] + (int)relp[node] : 0;
    }
    __syncthreads();

    const int e0 = s * SLICE_E;
    for (int j = tid; j < SLICE_E; j += 512) {
        int d = dst[e0 + j] - lo;
        if ((unsigned)d < RANGE_N) {
            int pos = atomicAdd(&cur[d], 1);
            csr_src[pos] = src[e0 + j];
        }
    }
}

// ---------------- GEMM1: bf16 MFMA 16x16x32, 64x64 tile, 2 chunks of BK=128 ----------------
// A fragment: row=lane&15, k=(lane>>4)*8+i.  B via transposed-W LDS: col=lane&15.
// D: col=lane&15, row=(lane>>4)*4+reg  [verified layouts, learn_hip m89/m91].
#define AST 136    // shorts per LDS row: 128 k + 8 pad (272 B rows -> 2-way-free b128 reads)
__global__ __launch_bounds__(256) void gemm1_kernel(const float* __restrict__ x,
                                                    const float* __restrict__ W1,
                                                    const float* __restrict__ norm_out,
                                                    u16* __restrict__ xw1) {
    __shared__ short As[64 * AST];   // x tile, bf16, [row][k]
    __shared__ short Bt[64 * AST];   // W1 chunk, bf16, [col][k]
    const int tid = threadIdx.x;
    const int n0 = blockIdx.x * 64;

    const f32x4 zero4 = {0.f, 0.f, 0.f, 0.f};
    f32x4 acc[4] = {zero4, zero4, zero4, zero4};

    const int srow = tid >> 2;          // staging row 0..63
    const int sseg = tid & 3;           // 32-k segment
    const int grow = n0 + srow;
    const bool grow_ok = grow < N_NODES;

    const int w = tid >> 6;             // wave 0..3 -> rows w*16..
    const int l = tid & 63;

    for (int c = 0; c < 2; ++c) {
        if (c) __syncthreads();         // protect LDS from previous chunk's readers
        // ---- stage x chunk: 64 rows x 128 k -> bf16 ----
        {
            const float* xp = x + (size_t)grow * IN_FEATS + c * 128 + sseg * 32;
            short* ap = As + srow * AST + sseg * 32;
#pragma unroll
            for (int j = 0; j < 8; ++j) {
                float4 v = make_float4(0.f, 0.f, 0.f, 0.f);
                if (grow_ok) v = *(const float4*)(xp + j * 4);
                unsigned p0 = f2bf_pk(v.x, v.y);
                unsigned p1 = f2bf_pk(v.z, v.w);
                *(uint2*)(ap + j * 4) = make_uint2(p0, p1);
            }
        }
        // ---- stage W1 chunk transposed: Bt[col][k], k-pairs packed ----
        {
#pragma unroll
            for (int it = 0; it < 16; ++it) {
                int flat = tid + it * 256;
                int kp = flat >> 6;             // k-pair 0..63
                int col = flat & 63;
                int k = c * 128 + kp * 2;
                float w0 = W1[(size_t)k * HIDDEN + col];
                float w1 = W1[(size_t)(k + 1) * HIDDEN + col];
                *(unsigned*)(Bt + col * AST + kp * 2) = f2bf_pk(w0, w1);
            }
        }
        __syncthreads();

        // ---- MFMA: 4 k-steps x 4 col-tiles ----
        const short* ap = As + (w * 16 + (l & 15)) * AST + (l >> 4) * 8;
        const short* bp = Bt + (l & 15) * AST + (l >> 4) * 8;
#pragma unroll
        for (int ks = 0; ks < 4; ++ks) {
            bf16x8 af = *(const bf16x8*)(ap + ks * 32);
#pragma unroll
            for (int ct = 0; ct < 4; ++ct) {
                bf16x8 bfv = *(const bf16x8*)(bp + ct * 16 * AST + ks * 32);
                acc[ct] = __builtin_amdgcn_mfma_f32_16x16x32_bf16(af, bfv, acc[ct], 0, 0, 0);
            }
        }
    }

    // ---- epilogue: D[row][col], row=(l>>4)*4+j, col=l&15; store bf16 ----
    const int rbase = n0 + w * 16 + (l >> 4) * 4;
    const int cbase = l & 15;
#pragma unroll
    for (int j = 0; j < 4; ++j) {
        int row = rbase + j;
        if (row < N_NODES) {
            float nrm = norm_out[row];
            u16* orow = xw1 + (size_t)row * HIDDEN + cbase;
#pragma unroll
            for (int ct = 0; ct < 4; ++ct)
                orow[ct * 16] = f2bf(acc[ct][j] * nrm);
        }
    }
}

// ---------------- GEMM2: xw2[n] = (g1[n] @ W2) * norm_out[n], bf16 out ----------------
__global__ __launch_bounds__(256) void gemm2_kernel(const float* __restrict__ g1,
                                                    const float* __restrict__ W2,
                                                    const float* __restrict__ norm_out,
                                                    u16* __restrict__ xw2) {
    __shared__ float gs[8][HIDDEN];
    __shared__ float ws[HIDDEN * OUTF];
    const int tid = threadIdx.x;
    const int n0 = blockIdx.x * 8;

#pragma unroll
    for (int i = 0; i < 8; ++i) ws[tid + i * 256] = W2[tid + i * 256];
    const float4* gv = (const float4*)(g1 + (size_t)n0 * HIDDEN);
    if (tid < 128) ((float4*)&gs[0][0])[tid] = gv[tid];
    __syncthreads();

    const int o = tid & 31;
    const int r = tid >> 5;
    float acc = 0.f;
#pragma unroll
    for (int k = 0; k < HIDDEN; ++k) acc += gs[r][k] * ws[k * OUTF + o];
    xw2[(size_t)(n0 + r) * OUTF + o] = f2bf(acc * norm_out[n0 + r]);
}

// ---------------- gather 64 feats (bf16 table): one wave per node, 8-deep MLP ----------------
__global__ __launch_bounds__(256) void gather64_kernel(const int* __restrict__ row_start,
                                                       const int* __restrict__ csr_src,
                                                       const u16* __restrict__ xw,
                                                       const float* __restrict__ norm_in,
                                                       const float* __restrict__ b,
                                                       float* __restrict__ g) {
    int n = blockIdx.x * 4 + (threadIdx.x >> 6);
    if (n >= N_NODES) return;
    int lane = threadIdx.x & 63;
    int beg = row_start[n], end = row_start[n + 1];
    float acc = 0.f;
    int i = beg;
    for (; i + 8 <= end; i += 8) {
        int s0 = csr_src[i + 0], s1 = csr_src[i + 1];
        int s2 = csr_src[i + 2], s3 = csr_src[i + 3];
        int s4 = csr_src[i + 4], s5 = csr_src[i + 5];
        int s6 = csr_src[i + 6], s7 = csr_src[i + 7];
        float v0 = bf2f(xw[(size_t)s0 * 64 + lane]);
        float v1 = bf2f(xw[(size_t)s1 * 64 + lane]);
        float v2 = bf2f(xw[(size_t)s2 * 64 + lane]);
        float v3 = bf2f(xw[(size_t)s3 * 64 + lane]);
        float v4 = bf2f(xw[(size_t)s4 * 64 + lane]);
        float v5 = bf2f(xw[(size_t)s5 * 64 + lane]);
        float v6 = bf2f(xw[(size_t)s6 * 64 + lane]);
        float v7 = bf2f(xw[(size_t)s7 * 64 + lane]);
        acc += ((v0 + v1) + (v2 + v3)) + ((v4 + v5) + (v6 + v7));
    }
    for (; i < end; ++i) acc += bf2f(xw[(size_t)csr_src[i] * 64 + lane]);
    g[(size_t)n * 64 + lane] = fmaxf(acc * norm_in[n] + b[lane], 0.f);
}

// ---------------- gather 32 feats (bf16 table): half-wave per node, 8-deep MLP ----------------
__global__ __launch_bounds__(256) void gather32_kernel(const int* __restrict__ row_start,
                                                       const int* __restrict__ csr_src,
                                                       const u16* __restrict__ xw,
                                                       const float* __restrict__ norm_in,
                                                       const float* __restrict__ b,
                                                       float* __restrict__ g) {
    int n = blockIdx.x * 8 + (threadIdx.x >> 5);
    if (n >= N_NODES) return;
    int lane = threadIdx.x & 31;
    int beg = row_start[n], end = row_start[n + 1];
    float acc = 0.f;
    int i = beg;
    for (; i + 8 <= end; i += 8) {
        int s0 = csr_src[i + 0], s1 = csr_src[i + 1];
        int s2 = csr_src[i + 2], s3 = csr_src[i + 3];
        int s4 = csr_src[i + 4], s5 = csr_src[i + 5];
        int s6 = csr_src[i + 6], s7 = csr_src[i + 7];
        float v0 = bf2f(xw[(size_t)s0 * 32 + lane]);
        float v1 = bf2f(xw[(size_t)s1 * 32 + lane]);
        float v2 = bf2f(xw[(size_t)s2 * 32 + lane]);
        float v3 = bf2f(xw[(size_t)s3 * 32 + lane]);
        float v4 = bf2f(xw[(size_t)s4 * 32 + lane]);
        float v5 = bf2f(xw[(size_t)s5 * 32 + lane]);
        float v6 = bf2f(xw[(size_t)s6 * 32 + lane]);
        float v7 = bf2f(xw[(size_t)s7 * 32 + lane]);
        acc += ((v0 + v1) + (v2 + v3)) + ((v4 + v5) + (v6 + v7));
    }
    for (; i < end; ++i) acc += bf2f(xw[(size_t)csr_src[i] * 32 + lane]);
    g[(size_t)n * 32 + lane] = fmaxf(acc * norm_in[n] + b[lane], 0.f);
}

// ---------------- final projection ----------------
__global__ __launch_bounds__(32) void init_out_kernel(float* __restrict__ out,
                                                      const float* __restrict__ fc_b) {
    out[threadIdx.x] = fc_b[0];
}

__global__ __launch_bounds__(256) void reduce_kernel(const float* __restrict__ g2,
                                                     const float* __restrict__ fc_w,
                                                     float* __restrict__ out) {
    __shared__ float s[OUTF];
    const int tid = threadIdx.x;
    if (tid < OUTF) s[tid] = 0.f;
    __syncthreads();

    const int f4 = tid & 7;
    int n = blockIdx.x * 32 + (tid >> 3);
    const int stride = gridDim.x * 32;
    float ax = 0.f, ay = 0.f, az = 0.f, aw = 0.f;
    for (; n < N_NODES; n += stride) {
        float w = fc_w[n];
        float4 g = ((const float4*)(g2 + (size_t)n * OUTF))[f4];
        ax += g.x * w; ay += g.y * w; az += g.z * w; aw += g.w * w;
    }
    atomicAdd(&s[f4 * 4 + 0], ax);
    atomicAdd(&s[f4 * 4 + 1], ay);
    atomicAdd(&s[f4 * 4 + 2], az);
    atomicAdd(&s[f4 * 4 + 3], aw);
    __syncthreads();
    if (tid < OUTF) atomicAdd(&out[tid], s[tid]);
}

extern "C" void kernel_launch(void* const* d_in, const int* in_sizes, int n_in,
                              void* d_out, int out_size, void* d_ws, size_t ws_size,
                              hipStream_t stream) {
    const float* x    = (const float*)d_in[0];
    const int*   src  = (const int*)d_in[1];
    const int*   dst  = (const int*)d_in[2];
    const float* W1   = (const float*)d_in[3];
    const float* b1   = (const float*)d_in[4];
    const float* W2   = (const float*)d_in[5];
    const float* b2   = (const float*)d_in[6];
    const float* fc_w = (const float*)d_in[7];
    const float* fc_b = (const float*)d_in[8];
    float* out = (float*)d_out;

    // ---- workspace layout: ints | floats | u8 partials ----
    int* ip = (int*)d_ws;
    int* csr_src      = ip;                 // 800000
    int* row_start    = ip + 800000;        // 50001
    int* block_sums   = ip + 850001;        // 256 (+3 pad)
    float* fp = (float*)(ip + 850260);
    u16* xw_buf     = (u16*)fp;             // 3.2M bf16 (uses half the old region)
    float* g_buf    = fp + 3200000;         // 3.2M floats
    float* norm_out = fp + 6400000;         // 50000
    float* norm_in  = fp + 6450000;         // 50000
    unsigned char* partial = (unsigned char*)(fp + 6500000); // 2*64*51200 B
    unsigned char* rel = partial + (size_t)NSLICE * PSTRIDE; // dst partials -> rel prefixes

    // ---- CSR build (no global atomics anywhere) ----
    hist_kernel<<<NSLICE * HRANGE * 2, 512, 0, stream>>>(src, dst, partial);
    reduce_scan_kernel<<<SCAN_BLOCKS, 256, 0, stream>>>(partial, row_start, block_sums,
                                                        norm_out, norm_in);
    scan3_kernel<<<SCAN_BLOCKS, 256, 0, stream>>>(row_start, block_sums);
    fill_csr_kernel<<<NSLICE * NRANGE, 512, 0, stream>>>(src, dst, row_start, rel, csr_src);

    // ---- layer 1 ----
    gemm1_kernel<<<(N_NODES + 63) / 64, 256, 0, stream>>>(x, W1, norm_out, xw_buf);
    gather64_kernel<<<(N_NODES + 3) / 4, 256, 0, stream>>>(row_start, csr_src, xw_buf,
                                                           norm_in, b1, g_buf);

    // ---- layer 2 ----
    gemm2_kernel<<<N_NODES / 8, 256, 0, stream>>>(g_buf, W2, norm_out, xw_buf);
    gather32_kernel<<<(N_NODES + 7) / 8, 256, 0, stream>>>(row_start, csr_src, xw_buf,
                                                           norm_in, b2, g_buf);

    // ---- final projection ----
    init_out_kernel<<<1, 32, 0, stream>>>(out, fc_b);
    reduce_kernel<<<512, 256, 0, stream>>>(g_buf, fc_w, out);
}